// Round 21
// baseline (166.285 us; speedup 1.0000x reference)
//
#include <hip/hip_runtime.h>
#include <math.h>

#define N_NODES 50000
#define N_EDGES 800000
#define IN_F 128
#define OUT_F 64
#define LRELU_ALPHA 0.2f

#define NPB 64                               // nodes per bucket (power of 2)
#define NBUCK ((N_NODES + NPB - 1) / NPB)    // 782
#define EPT 16                               // edges per thread (scatter)
#define NBT ((N_EDGES / EPT + 255) / 256)    // 196 blocks
#define CHUNK 2048                           // gather chunk (edges)

typedef __attribute__((ext_vector_type(8))) short bf16x8;
typedef __attribute__((ext_vector_type(4))) float f32x4;

__device__ inline float wred_sum(float v) {
#pragma unroll
    for (int o = 32; o > 0; o >>= 1) v += __shfl_down(v, o, 64);
    return v;
}

__device__ inline unsigned bf16r(float f) {  // round-to-nearest-even bf16 (as u16)
    unsigned u = __float_as_uint(f);
    u += 0x7fffu + ((u >> 16) & 1u);
    return u >> 16;
}

// K1 (fused): per-block W->bf16 swizzled LDS + wt/wb recompute + x->bf16 LDS
// + exact f32 sv/tv + MFMA GEMM -> split Whb_lo/Whb_hi + fused bucket hist.
__global__ __launch_bounds__(256, 4) void k_wh(const float* __restrict__ x,
                                               const float* __restrict__ W,
                                               const float* __restrict__ a,
                                               const int* __restrict__ src,
                                               unsigned short* __restrict__ Whb_lo,
                                               unsigned short* __restrict__ Whb_hi,
                                               float* __restrict__ sv,
                                               float* __restrict__ tv,
                                               int* __restrict__ bcnt) {
    __shared__ unsigned short xb[64 * 128];   // bf16 x tile, swizzled (16 KB)
    __shared__ unsigned short wtl[64 * 128];  // bf16 W^T, swizzled (16 KB)
    __shared__ float wt_s[128], wb_s[128];
    __shared__ int hc[NBUCK];

    const int tid = threadIdx.x;
    const int row0 = blockIdx.x * 64;

    for (int i = tid; i < NBUCK; i += 256) hc[i] = 0;

    // phase A1: stage W (f32 global) -> wtl = bf16 W^T, swizzled
    for (int i = tid; i < 2048; i += 256) {
        int k = i >> 4, c4 = (i & 15) << 2;
        float4 wv = *reinterpret_cast<const float4*>(W + k * 64 + c4);
        int kb = k >> 3, kr = k & 7;
        wtl[(c4 + 0) * 128 + ((kb ^ ((c4 + 0) & 15)) << 3) + kr] = (unsigned short)bf16r(wv.x);
        wtl[(c4 + 1) * 128 + ((kb ^ ((c4 + 1) & 15)) << 3) + kr] = (unsigned short)bf16r(wv.y);
        wtl[(c4 + 2) * 128 + ((kb ^ ((c4 + 2) & 15)) << 3) + kr] = (unsigned short)bf16r(wv.z);
        wtl[(c4 + 3) * 128 + ((kb ^ ((c4 + 3) & 15)) << 3) + kr] = (unsigned short)bf16r(wv.w);
    }

    // phase A2: wt = W@a_top, wb = W@a_bot (exact f32, identical per block)
    if (tid < 128) {
        int k = tid;
        float s = 0.0f, t = 0.0f;
#pragma unroll
        for (int c4 = 0; c4 < 64; c4 += 4) {
            float4 wv = *reinterpret_cast<const float4*>(W + k * 64 + c4);
            float4 at = *reinterpret_cast<const float4*>(a + c4);
            float4 ab = *reinterpret_cast<const float4*>(a + 64 + c4);
            s = fmaf(wv.w, at.w, fmaf(wv.z, at.z, fmaf(wv.y, at.y, fmaf(wv.x, at.x, s))));
            t = fmaf(wv.w, ab.w, fmaf(wv.z, ab.z, fmaf(wv.y, ab.y, fmaf(wv.x, ab.x, t))));
        }
        wt_s[k] = s;
        wb_s[k] = t;
    }

    // phase A3: histogram this block's 1024 edges into LDS
    {
        int j0 = blockIdx.x * 1024 + tid * 4;
        if (j0 < N_EDGES) {
            int4 s4 = *reinterpret_cast<const int4*>(src + j0);
            atomicAdd(&hc[s4.x >> 6], 1);
            atomicAdd(&hc[s4.y >> 6], 1);
            atomicAdd(&hc[s4.z >> 6], 1);
            atomicAdd(&hc[s4.w >> 6], 1);
        }
    }
    __syncthreads();

    // phase B: stage x -> xb (bf16, swizzled) + f32 sv/tv partial dots
    const int cc = (tid & 31) << 2;
    float4 wt4 = *reinterpret_cast<const float4*>(wt_s + cc);
    float4 wb4 = *reinterpret_cast<const float4*>(wb_s + cc);
    float ps[8], pt[8];
#pragma unroll
    for (int it = 0; it < 8; ++it) {
        int i = tid + it * 256;
        int rl = i >> 5;
        int r = row0 + rl;
        float4 v = make_float4(0.f, 0.f, 0.f, 0.f);
        if (r < N_NODES) v = *reinterpret_cast<const float4*>(x + (size_t)r * IN_F + cc);
        ps[it] = fmaf(v.w, wt4.w, fmaf(v.z, wt4.z, fmaf(v.y, wt4.y, v.x * wt4.x)));
        pt[it] = fmaf(v.w, wb4.w, fmaf(v.z, wb4.z, fmaf(v.y, wb4.y, v.x * wb4.x)));
        int kb = cc >> 3;
        uint2 pk;
        pk.x = bf16r(v.x) | (bf16r(v.y) << 16);
        pk.y = bf16r(v.z) | (bf16r(v.w) << 16);
        *reinterpret_cast<uint2*>(
            &xb[rl * 128 + (kb ^ (rl & 15)) * 8 + ((cc >> 2) & 1) * 4]) = pk;
    }
    __syncthreads();

    // phase C: MFMA
    const int l = tid & 63, w = tid >> 6;
    const int rloc0 = w * 16;
    const int arow = rloc0 + (l & 15);
    const int kgrp = l >> 4;
    f32x4 acc[4] = {f32x4{0,0,0,0}, f32x4{0,0,0,0}, f32x4{0,0,0,0}, f32x4{0,0,0,0}};
#pragma unroll
    for (int t = 0; t < 4; ++t) {
        int kb = t * 4 + kgrp;
        bf16x8 af = *reinterpret_cast<const bf16x8*>(
            &xb[arow * 128 + (kb ^ (arow & 15)) * 8]);
#pragma unroll
        for (int ct = 0; ct < 4; ++ct) {
            int brow = ct * 16 + (l & 15);
            bf16x8 bfr = *reinterpret_cast<const bf16x8*>(
                &wtl[brow * 128 + (kb ^ (brow & 15)) * 8]);
            acc[ct] = __builtin_amdgcn_mfma_f32_16x16x32_bf16(af, bfr, acc[ct], 0, 0, 0);
        }
    }

    // epilogue: split halves — cols 0-31 -> Whb_lo, 32-63 -> Whb_hi
#pragma unroll
    for (int ct = 0; ct < 4; ++ct) {
#pragma unroll
        for (int i = 0; i < 4; ++i) {
            int r = row0 + rloc0 + (l >> 4) * 4 + i;
            if (r < N_NODES) {
                unsigned short v = (unsigned short)bf16r(acc[ct][i]);
                if (ct < 2)
                    Whb_lo[(size_t)r * 32 + ct * 16 + (l & 15)] = v;
                else
                    Whb_hi[(size_t)r * 32 + (ct - 2) * 16 + (l & 15)] = v;
            }
        }
    }

#pragma unroll
    for (int it = 0; it < 8; ++it) {
        float s = ps[it], t2 = pt[it];
#pragma unroll
        for (int o = 1; o < 32; o <<= 1) {
            s += __shfl_xor(s, o, 64);
            t2 += __shfl_xor(t2, o, 64);
        }
        int r = row0 + (tid >> 5) + it * 8;
        if ((tid & 31) == 0 && r < N_NODES) { sv[r] = s; tv[r] = t2; }
    }

    // flush histogram (hc finalized before first sync)
    for (int i = tid; i < NBUCK; i += 256) {
        int v = hc[i];
        if (v) atomicAdd(&bcnt[i], v);
    }
}

// exclusive scan of 782 bucket counts: shfl-scan per wave + serial combine
__global__ __launch_bounds__(1024) void k_bscan(const int* __restrict__ bcnt,
                                                int* __restrict__ bbase,
                                                int* __restrict__ cursor) {
    __shared__ int wsum[16], woff[16];
    int t = threadIdx.x, lane = t & 63, w = t >> 6;
    int c = (t < NBUCK) ? bcnt[t] : 0;
    int run = c;
#pragma unroll
    for (int o = 1; o < 64; o <<= 1) {
        int v = __shfl_up(run, o, 64);
        if (lane >= o) run += v;
    }
    if (lane == 63) wsum[w] = run;
    __syncthreads();
    if (t == 0) {
        int r = 0;
#pragma unroll
        for (int i = 0; i < 16; i++) { woff[i] = r; r += wsum[i]; }
    }
    __syncthreads();
    int ex = run - c + woff[w];
    if (t < NBUCK) {
        bbase[t] = ex;
        cursor[t] = ex;
    }
    if (t == 0) bbase[NBUCK] = N_EDGES;
}

// bucket scatter: EPT=16; LDS ranks + one global reserve atomic per
// (block,bucket); stores rec = {dst|local<<16, bits(exp(v))} (gmax cancels).
__global__ __launch_bounds__(256) void k_binscatter(const int* __restrict__ src,
                                                    const int* __restrict__ dst,
                                                    const float* __restrict__ sv,
                                                    const float* __restrict__ tv,
                                                    int* __restrict__ cursor,
                                                    int2* __restrict__ rec,
                                                    float* __restrict__ psum) {
    __shared__ int lcnt[NBUCK];
    __shared__ int lbase[NBUCK];
    const int tid = threadIdx.x;
    for (int i = tid; i < NBUCK; i += 256) lcnt[i] = 0;
    __syncthreads();

    int t = blockIdx.x * 256 + tid;
    int j0 = t * EPT;
    bool ok = (j0 < N_EDGES);

    int s_[EPT], d_[EPT], rk[EPT];
    float ev[EPT];
    float lsum = 0.0f;
    if (ok) {
#pragma unroll
        for (int q = 0; q < 4; q++) {
            int4 s4 = *reinterpret_cast<const int4*>(src + j0 + q * 4);
            int4 d4 = *reinterpret_cast<const int4*>(dst + j0 + q * 4);
            s_[q * 4 + 0] = s4.x; s_[q * 4 + 1] = s4.y;
            s_[q * 4 + 2] = s4.z; s_[q * 4 + 3] = s4.w;
            d_[q * 4 + 0] = d4.x; d_[q * 4 + 1] = d4.y;
            d_[q * 4 + 2] = d4.z; d_[q * 4 + 3] = d4.w;
        }
        float svv[EPT], tvv[EPT];
#pragma unroll
        for (int k = 0; k < EPT; k++) svv[k] = sv[s_[k]];
#pragma unroll
        for (int k = 0; k < EPT; k++) tvv[k] = tv[d_[k]];
#pragma unroll
        for (int k = 0; k < EPT; k++) {
            float vv = svv[k] + tvv[k];
            vv = vv > 0.0f ? vv : LRELU_ALPHA * vv;
            float e = __expf(vv);
            ev[k] = e;
            lsum += e;
        }
#pragma unroll
        for (int k = 0; k < EPT; k++) rk[k] = atomicAdd(&lcnt[s_[k] >> 6], 1);
    }
    __syncthreads();

    for (int i = tid; i < NBUCK; i += 256) {
        int c = lcnt[i];
        lbase[i] = c ? atomicAdd(&cursor[i], c) : 0;
    }
    __syncthreads();

    if (ok) {
#pragma unroll
        for (int k = 0; k < EPT; k++) {
            int b = s_[k] >> 6;
            rec[lbase[b] + rk[k]] =
                make_int2(d_[k] | ((s_[k] & (NPB - 1)) << 16), __float_as_int(ev[k]));
        }
    }

    float wsum = wred_sum(lsum);
    __shared__ float rsm[4];
    if ((tid & 63) == 0) rsm[tid >> 6] = wsum;
    __syncthreads();
    if (tid == 0)
        psum[blockIdx.x] = rsm[0] + rsm[1] + rsm[2] + rsm[3];
}

// bucket gather: NPB=64, 512 threads (8 waves), fused 1/sum reduce,
// in-LDS counting sort once per chunk, then TWO feature-half passes
// (each over a 3.2 MB L2-resident table). Quarter-wave (16 lanes) per edge:
// lane = q*16 + j2, features (2*j2, 2*j2+1) of the half.
__global__ __launch_bounds__(512) void k_bgather(const int* __restrict__ bbase,
                                                 const int2* __restrict__ rec,
                                                 const float* __restrict__ psum,
                                                 const unsigned short* __restrict__ Whb_lo,
                                                 const unsigned short* __restrict__ Whb_hi,
                                                 float* __restrict__ out) {
    __shared__ int2 sorted[CHUNK];               // 16 KB
    __shared__ int scnt[NPB], soff[NPB], shead[NPB];
    __shared__ float ginv_s;

    const int tid = threadIdx.x;
    const int lane = tid & 63, w = tid >> 6;     // wave 0..7
    const int j2 = lane & 15, qd = lane >> 4;    // feature-pair, quarter id
    const int b = blockIdx.x;
    const int e0 = bbase[b], e1 = bbase[b + 1];

    // fused: ginv = 1 / sum(psum[0..NBT))
    if (tid < 64) {
        float lsum = 0.0f;
        for (int i = tid; i < NBT; i += 64) lsum += psum[i];
        float ws = wred_sum(lsum);
        if (tid == 0) ginv_s = 1.0f / ws;
    }
    __syncthreads();
    const float ginv = ginv_s;

    float ax[2][8], ay[2][8];
#pragma unroll
    for (int p = 0; p < 2; p++)
#pragma unroll
        for (int k = 0; k < 8; k++) { ax[p][k] = 0.0f; ay[p][k] = 0.0f; }

    for (int base = e0; base < e1; base += CHUNK) {
        int m = e1 - base;
        if (m > CHUNK) m = CHUNK;

        int2 rr[4];
        int ln[4];
        bool vv[4];
        if (tid < NPB) scnt[tid] = 0;
        __syncthreads();
#pragma unroll
        for (int q = 0; q < 4; q++) {
            int idx = tid + q * 512;
            vv[q] = idx < m;
            rr[q] = make_int2(0, 0);
            ln[q] = 0;
            if (vv[q]) {
                rr[q] = rec[base + idx];
                ln[q] = (rr[q].x >> 16) & (NPB - 1);
                atomicAdd(&scnt[ln[q]], 1);
            }
        }
        __syncthreads();

        if (tid < 64) {
            int c = scnt[tid];
            int run = c;
#pragma unroll
            for (int o = 1; o < 64; o <<= 1) {
                int src_ln = (tid >= o) ? (tid - o) : tid;
                int t2 = __shfl(run, src_ln, 64);
                if (tid >= o) run += t2;
            }
            int excl = run - c;
            soff[tid] = excl;
            shead[tid] = excl;
        }
        __syncthreads();

#pragma unroll
        for (int q = 0; q < 4; q++) {
            if (vv[q]) {
                int pos = atomicAdd(&shead[ln[q]], 1);
                sorted[pos] = make_int2(rr[q].x & 0xFFFF, rr[q].y);
            }
        }
        __syncthreads();

        // two feature-half passes over the sorted chunk
#pragma unroll
        for (int p = 0; p < 2; p++) {
            const unsigned short* Wp = p ? Whb_hi : Whb_lo;
#pragma unroll
            for (int k = 0; k < 8; k++) {
                int node = w * 8 + k;
                int lo = soff[node], c = scnt[node];
                float px = 0.0f, py = 0.0f;
                int i = 0;
                for (; i + 7 < c; i += 8) {      // 8 edges, 2 loads/lane
                    int2 q0 = sorted[lo + i + qd];
                    int2 q1 = sorted[lo + i + 4 + qd];
                    unsigned u0 = reinterpret_cast<const unsigned*>(
                        Wp + (size_t)q0.x * 32)[j2];
                    unsigned u1 = reinterpret_cast<const unsigned*>(
                        Wp + (size_t)q1.x * 32)[j2];
                    float att0 = __int_as_float(q0.y);
                    float att1 = __int_as_float(q1.y);
                    px = fmaf(att0, __uint_as_float((u0 & 0xffffu) << 16), px);
                    py = fmaf(att0, __uint_as_float(u0 & 0xffff0000u), py);
                    px = fmaf(att1, __uint_as_float((u1 & 0xffffu) << 16), px);
                    py = fmaf(att1, __uint_as_float(u1 & 0xffff0000u), py);
                }
                for (; i < c; i += 4) {          // tail quad (maybe part-valid)
                    int ii = i + qd;
                    bool val = ii < c;
                    int2 q = sorted[lo + (val ? ii : i)];
                    unsigned u = reinterpret_cast<const unsigned*>(
                        Wp + (size_t)q.x * 32)[j2];
                    float att = val ? __int_as_float(q.y) : 0.0f;
                    px = fmaf(att, __uint_as_float((u & 0xffffu) << 16), px);
                    py = fmaf(att, __uint_as_float(u & 0xffff0000u), py);
                }
                ax[p][k] += px;
                ay[p][k] += py;
            }
        }
        __syncthreads();
    }

    // combine quarters; lanes qd==0 write float2, ELU + ginv fused
#pragma unroll
    for (int p = 0; p < 2; p++) {
#pragma unroll
        for (int k = 0; k < 8; k++) {
            float sx = ax[p][k] + __shfl_down(ax[p][k], 32, 64);
            sx += __shfl_down(sx, 16, 64);
            float sy = ay[p][k] + __shfl_down(ay[p][k], 32, 64);
            sy += __shfl_down(sy, 16, 64);
            int n = b * NPB + w * 8 + k;
            if (qd == 0 && n < N_NODES) {
                float2 v;
                v.x = sx * ginv;
                v.y = sy * ginv;
                v.x = v.x > 0.0f ? v.x : expm1f(v.x);
                v.y = v.y > 0.0f ? v.y : expm1f(v.y);
                *reinterpret_cast<float2*>(
                    out + (size_t)n * OUT_F + p * 32 + 2 * j2) = v;
            }
        }
    }
}

extern "C" void kernel_launch(void* const* d_in, const int* in_sizes, int n_in,
                              void* d_out, int out_size, void* d_ws, size_t ws_size,
                              hipStream_t stream) {
    const float* x  = (const float*)d_in[0];
    const int*   ei = (const int*)d_in[1];
    const float* W  = (const float*)d_in[2];
    const float* a  = (const float*)d_in[3];
    float* out = (float*)d_out;

    const int* src = ei;            // edge_index[0]
    const int* dst = ei + N_EDGES;  // edge_index[1]

    unsigned short* Whb_lo = (unsigned short*)d_ws;             // 1.6M u16 = 3.2 MB
    unsigned short* Whb_hi = Whb_lo + (size_t)N_NODES * 32;     // 3.2 MB
    float* sv     = (float*)(Whb_hi + (size_t)N_NODES * 32);    // 50,000 f
    float* tv     = sv + N_NODES;                     // 50,000 f
    float* psum   = tv + N_NODES;                     // 512 f
    int*   bcnt   = (int*)(psum + 512);               // NBUCK i
    int*   bbase  = bcnt + NBUCK;                     // NBUCK+1 i
    int*   cursor = bbase + NBUCK + 1;                // NBUCK i
    size_t used = (size_t)((char*)(cursor + NBUCK) - (char*)d_ws);
    used = (used + 15) & ~(size_t)15;
    int2*  rec  = (int2*)((char*)d_ws + used);        // 800,000 int2 = 6.4 MB

    hipMemsetAsync(bcnt, 0, NBUCK * sizeof(int), stream);
    k_wh<<<(N_NODES + 63) / 64, 256, 0, stream>>>(x, W, a, src, Whb_lo, Whb_hi,
                                                  sv, tv, bcnt);
    k_bscan<<<1, 1024, 0, stream>>>(bcnt, bbase, cursor);
    k_binscatter<<<NBT, 256, 0, stream>>>(src, dst, sv, tv, cursor, rec, psum);
    k_bgather<<<NBUCK, 512, 0, stream>>>(bbase, rec, psum, Whb_lo, Whb_hi, out);
}

// Round 22
// 102.186 us; speedup vs baseline: 1.6273x; 1.6273x over previous
//
#include <hip/hip_runtime.h>
#include <math.h>

#define N_NODES 50000
#define N_EDGES 800000
#define IN_F 128
#define OUT_F 64
#define LRELU_ALPHA 0.2f

#define NPB 64                               // nodes per bucket (power of 2)
#define NBUCK ((N_NODES + NPB - 1) / NPB)    // 782
#define EPT 16                               // edges per thread (scatter)
#define NBT ((N_EDGES / EPT + 255) / 256)    // 196 blocks
#define CHUNK 2048                           // gather chunk (edges)

typedef __attribute__((ext_vector_type(8))) short bf16x8;
typedef __attribute__((ext_vector_type(4))) float f32x4;

__device__ inline float wred_sum(float v) {
#pragma unroll
    for (int o = 32; o > 0; o >>= 1) v += __shfl_down(v, o, 64);
    return v;
}

__device__ inline unsigned bf16r(float f) {  // round-to-nearest-even bf16 (as u16)
    unsigned u = __float_as_uint(f);
    u += 0x7fffu + ((u >> 16) & 1u);
    return u >> 16;
}

// K1 (fused): per-block W->bf16 swizzled LDS + wt/wb recompute + x->bf16 LDS
// + exact f32 sv/tv + MFMA GEMM -> Whb + fused bucket histogram.
__global__ __launch_bounds__(256, 4) void k_wh(const float* __restrict__ x,
                                               const float* __restrict__ W,
                                               const float* __restrict__ a,
                                               const int* __restrict__ src,
                                               unsigned short* __restrict__ Whb,
                                               float* __restrict__ sv,
                                               float* __restrict__ tv,
                                               int* __restrict__ bcnt) {
    __shared__ unsigned short xb[64 * 128];   // bf16 x tile, swizzled (16 KB)
    __shared__ unsigned short wtl[64 * 128];  // bf16 W^T, swizzled (16 KB)
    __shared__ float wt_s[128], wb_s[128];
    __shared__ int hc[NBUCK];

    const int tid = threadIdx.x;
    const int row0 = blockIdx.x * 64;

    for (int i = tid; i < NBUCK; i += 256) hc[i] = 0;

    // phase A1: stage W (f32 global) -> wtl = bf16 W^T, swizzled
    for (int i = tid; i < 2048; i += 256) {
        int k = i >> 4, c4 = (i & 15) << 2;
        float4 wv = *reinterpret_cast<const float4*>(W + k * 64 + c4);
        int kb = k >> 3, kr = k & 7;
        wtl[(c4 + 0) * 128 + ((kb ^ ((c4 + 0) & 15)) << 3) + kr] = (unsigned short)bf16r(wv.x);
        wtl[(c4 + 1) * 128 + ((kb ^ ((c4 + 1) & 15)) << 3) + kr] = (unsigned short)bf16r(wv.y);
        wtl[(c4 + 2) * 128 + ((kb ^ ((c4 + 2) & 15)) << 3) + kr] = (unsigned short)bf16r(wv.z);
        wtl[(c4 + 3) * 128 + ((kb ^ ((c4 + 3) & 15)) << 3) + kr] = (unsigned short)bf16r(wv.w);
    }

    // phase A2: wt = W@a_top, wb = W@a_bot (exact f32, identical per block)
    if (tid < 128) {
        int k = tid;
        float s = 0.0f, t = 0.0f;
#pragma unroll
        for (int c4 = 0; c4 < 64; c4 += 4) {
            float4 wv = *reinterpret_cast<const float4*>(W + k * 64 + c4);
            float4 at = *reinterpret_cast<const float4*>(a + c4);
            float4 ab = *reinterpret_cast<const float4*>(a + 64 + c4);
            s = fmaf(wv.w, at.w, fmaf(wv.z, at.z, fmaf(wv.y, at.y, fmaf(wv.x, at.x, s))));
            t = fmaf(wv.w, ab.w, fmaf(wv.z, ab.z, fmaf(wv.y, ab.y, fmaf(wv.x, ab.x, t))));
        }
        wt_s[k] = s;
        wb_s[k] = t;
    }

    // phase A3: histogram this block's 1024 edges into LDS
    {
        int j0 = blockIdx.x * 1024 + tid * 4;
        if (j0 < N_EDGES) {
            int4 s4 = *reinterpret_cast<const int4*>(src + j0);
            atomicAdd(&hc[s4.x >> 6], 1);
            atomicAdd(&hc[s4.y >> 6], 1);
            atomicAdd(&hc[s4.z >> 6], 1);
            atomicAdd(&hc[s4.w >> 6], 1);
        }
    }
    __syncthreads();

    // phase B: stage x -> xb (bf16, swizzled) + f32 sv/tv partial dots
    const int cc = (tid & 31) << 2;
    float4 wt4 = *reinterpret_cast<const float4*>(wt_s + cc);
    float4 wb4 = *reinterpret_cast<const float4*>(wb_s + cc);
    float ps[8], pt[8];
#pragma unroll
    for (int it = 0; it < 8; ++it) {
        int i = tid + it * 256;
        int rl = i >> 5;
        int r = row0 + rl;
        float4 v = make_float4(0.f, 0.f, 0.f, 0.f);
        if (r < N_NODES) v = *reinterpret_cast<const float4*>(x + (size_t)r * IN_F + cc);
        ps[it] = fmaf(v.w, wt4.w, fmaf(v.z, wt4.z, fmaf(v.y, wt4.y, v.x * wt4.x)));
        pt[it] = fmaf(v.w, wb4.w, fmaf(v.z, wb4.z, fmaf(v.y, wb4.y, v.x * wb4.x)));
        int kb = cc >> 3;
        uint2 pk;
        pk.x = bf16r(v.x) | (bf16r(v.y) << 16);
        pk.y = bf16r(v.z) | (bf16r(v.w) << 16);
        *reinterpret_cast<uint2*>(
            &xb[rl * 128 + (kb ^ (rl & 15)) * 8 + ((cc >> 2) & 1) * 4]) = pk;
    }
    __syncthreads();

    // phase C: MFMA
    const int l = tid & 63, w = tid >> 6;
    const int rloc0 = w * 16;
    const int arow = rloc0 + (l & 15);
    const int kgrp = l >> 4;
    f32x4 acc[4] = {f32x4{0,0,0,0}, f32x4{0,0,0,0}, f32x4{0,0,0,0}, f32x4{0,0,0,0}};
#pragma unroll
    for (int t = 0; t < 4; ++t) {
        int kb = t * 4 + kgrp;
        bf16x8 af = *reinterpret_cast<const bf16x8*>(
            &xb[arow * 128 + (kb ^ (arow & 15)) * 8]);
#pragma unroll
        for (int ct = 0; ct < 4; ++ct) {
            int brow = ct * 16 + (l & 15);
            bf16x8 bfr = *reinterpret_cast<const bf16x8*>(
                &wtl[brow * 128 + (kb ^ (brow & 15)) * 8]);
            acc[ct] = __builtin_amdgcn_mfma_f32_16x16x32_bf16(af, bfr, acc[ct], 0, 0, 0);
        }
    }

#pragma unroll
    for (int ct = 0; ct < 4; ++ct) {
#pragma unroll
        for (int i = 0; i < 4; ++i) {
            int r = row0 + rloc0 + (l >> 4) * 4 + i;
            if (r < N_NODES)
                Whb[(size_t)r * OUT_F + ct * 16 + (l & 15)] =
                    (unsigned short)bf16r(acc[ct][i]);
        }
    }

#pragma unroll
    for (int it = 0; it < 8; ++it) {
        float s = ps[it], t2 = pt[it];
#pragma unroll
        for (int o = 1; o < 32; o <<= 1) {
            s += __shfl_xor(s, o, 64);
            t2 += __shfl_xor(t2, o, 64);
        }
        int r = row0 + (tid >> 5) + it * 8;
        if ((tid & 31) == 0 && r < N_NODES) { sv[r] = s; tv[r] = t2; }
    }

    // flush histogram (hc finalized before first sync)
    for (int i = tid; i < NBUCK; i += 256) {
        int v = hc[i];
        if (v) atomicAdd(&bcnt[i], v);
    }
}

// exclusive scan of 782 bucket counts: shfl-scan per wave + serial combine
__global__ __launch_bounds__(1024) void k_bscan(const int* __restrict__ bcnt,
                                                int* __restrict__ bbase,
                                                int* __restrict__ cursor) {
    __shared__ int wsum[16], woff[16];
    int t = threadIdx.x, lane = t & 63, w = t >> 6;
    int c = (t < NBUCK) ? bcnt[t] : 0;
    int run = c;
#pragma unroll
    for (int o = 1; o < 64; o <<= 1) {
        int v = __shfl_up(run, o, 64);
        if (lane >= o) run += v;
    }
    if (lane == 63) wsum[w] = run;
    __syncthreads();
    if (t == 0) {
        int r = 0;
#pragma unroll
        for (int i = 0; i < 16; i++) { woff[i] = r; r += wsum[i]; }
    }
    __syncthreads();
    int ex = run - c + woff[w];
    if (t < NBUCK) {
        bbase[t] = ex;
        cursor[t] = ex;
    }
    if (t == 0) bbase[NBUCK] = N_EDGES;
}

// bucket scatter: EPT=16; LDS ranks + one global reserve atomic per
// (block,bucket); stores rec = {dst|local<<16, bits(exp(v))} (gmax cancels).
__global__ __launch_bounds__(256) void k_binscatter(const int* __restrict__ src,
                                                    const int* __restrict__ dst,
                                                    const float* __restrict__ sv,
                                                    const float* __restrict__ tv,
                                                    int* __restrict__ cursor,
                                                    int2* __restrict__ rec,
                                                    float* __restrict__ psum) {
    __shared__ int lcnt[NBUCK];
    __shared__ int lbase[NBUCK];
    const int tid = threadIdx.x;
    for (int i = tid; i < NBUCK; i += 256) lcnt[i] = 0;
    __syncthreads();

    int t = blockIdx.x * 256 + tid;
    int j0 = t * EPT;
    bool ok = (j0 < N_EDGES);

    int s_[EPT], d_[EPT], rk[EPT];
    float ev[EPT];
    float lsum = 0.0f;
    if (ok) {
#pragma unroll
        for (int q = 0; q < 4; q++) {
            int4 s4 = *reinterpret_cast<const int4*>(src + j0 + q * 4);
            int4 d4 = *reinterpret_cast<const int4*>(dst + j0 + q * 4);
            s_[q * 4 + 0] = s4.x; s_[q * 4 + 1] = s4.y;
            s_[q * 4 + 2] = s4.z; s_[q * 4 + 3] = s4.w;
            d_[q * 4 + 0] = d4.x; d_[q * 4 + 1] = d4.y;
            d_[q * 4 + 2] = d4.z; d_[q * 4 + 3] = d4.w;
        }
        float svv[EPT], tvv[EPT];
#pragma unroll
        for (int k = 0; k < EPT; k++) svv[k] = sv[s_[k]];
#pragma unroll
        for (int k = 0; k < EPT; k++) tvv[k] = tv[d_[k]];
#pragma unroll
        for (int k = 0; k < EPT; k++) {
            float vv = svv[k] + tvv[k];
            vv = vv > 0.0f ? vv : LRELU_ALPHA * vv;
            float e = __expf(vv);
            ev[k] = e;
            lsum += e;
        }
#pragma unroll
        for (int k = 0; k < EPT; k++) rk[k] = atomicAdd(&lcnt[s_[k] >> 6], 1);
    }
    __syncthreads();

    for (int i = tid; i < NBUCK; i += 256) {
        int c = lcnt[i];
        lbase[i] = c ? atomicAdd(&cursor[i], c) : 0;
    }
    __syncthreads();

    if (ok) {
#pragma unroll
        for (int k = 0; k < EPT; k++) {
            int b = s_[k] >> 6;
            rec[lbase[b] + rk[k]] =
                make_int2(d_[k] | ((s_[k] & (NPB - 1)) << 16), __float_as_int(ev[k]));
        }
    }

    float wsum = wred_sum(lsum);
    __shared__ float rsm[4];
    if ((tid & 63) == 0) rsm[tid >> 6] = wsum;
    __syncthreads();
    if (tid == 0)
        psum[blockIdx.x] = rsm[0] + rsm[1] + rsm[2] + rsm[3];
}

// bucket gather: NPB=64, 512 threads (8 waves), fused 1/sum reduce,
// in-LDS counting sort + half-wave bf16 accumulate (8 edges/iter).
__global__ __launch_bounds__(512) void k_bgather(const int* __restrict__ bbase,
                                                 const int2* __restrict__ rec,
                                                 const float* __restrict__ psum,
                                                 const unsigned short* __restrict__ Whb,
                                                 float* __restrict__ out) {
    __shared__ int2 sorted[CHUNK];               // 16 KB
    __shared__ int scnt[NPB], soff[NPB], shead[NPB];
    __shared__ float ginv_s;

    const int tid = threadIdx.x;
    const int lane = tid & 63, w = tid >> 6;     // wave 0..7
    const int j = lane & 31, h = lane >> 5;      // feature-pair, half id
    const int b = blockIdx.x;
    const int e0 = bbase[b], e1 = bbase[b + 1];

    // fused: ginv = 1 / sum(psum[0..NBT))
    if (tid < 64) {
        float lsum = 0.0f;
        for (int i = tid; i < NBT; i += 64) lsum += psum[i];
        float ws = wred_sum(lsum);
        if (tid == 0) ginv_s = 1.0f / ws;
    }
    __syncthreads();
    const float ginv = ginv_s;

    float ax[8], ay[8];
#pragma unroll
    for (int k = 0; k < 8; k++) { ax[k] = 0.0f; ay[k] = 0.0f; }

    for (int base = e0; base < e1; base += CHUNK) {
        int m = e1 - base;
        if (m > CHUNK) m = CHUNK;

        int2 rr[4];
        int ln[4];
        bool vv[4];
        if (tid < NPB) scnt[tid] = 0;
        __syncthreads();
#pragma unroll
        for (int q = 0; q < 4; q++) {
            int idx = tid + q * 512;
            vv[q] = idx < m;
            rr[q] = make_int2(0, 0);
            ln[q] = 0;
            if (vv[q]) {
                rr[q] = rec[base + idx];
                ln[q] = (rr[q].x >> 16) & (NPB - 1);
                atomicAdd(&scnt[ln[q]], 1);
            }
        }
        __syncthreads();

        if (tid < 64) {
            int c = scnt[tid];
            int run = c;
#pragma unroll
            for (int o = 1; o < 64; o <<= 1) {
                int src_ln = (tid >= o) ? (tid - o) : tid;
                int t2 = __shfl(run, src_ln, 64);
                if (tid >= o) run += t2;
            }
            int excl = run - c;
            soff[tid] = excl;
            shead[tid] = excl;
        }
        __syncthreads();

#pragma unroll
        for (int q = 0; q < 4; q++) {
            if (vv[q]) {
                int pos = atomicAdd(&shead[ln[q]], 1);
                sorted[pos] = make_int2(rr[q].x & 0xFFFF, rr[q].y);
            }
        }
        __syncthreads();

#pragma unroll
        for (int k = 0; k < 8; k++) {
            int node = w * 8 + k;
            int lo = soff[node], c = scnt[node];
            float px = 0.0f, py = 0.0f;
            int i = 0;
            for (; i + 7 < c; i += 8) {          // 8 edges, 4 loads in flight
                int2 q0 = sorted[lo + i + h];
                int2 q1 = sorted[lo + i + 2 + h];
                int2 q2 = sorted[lo + i + 4 + h];
                int2 q3 = sorted[lo + i + 6 + h];
                unsigned u0 = reinterpret_cast<const unsigned*>(
                    Whb + (size_t)q0.x * OUT_F)[j];
                unsigned u1 = reinterpret_cast<const unsigned*>(
                    Whb + (size_t)q1.x * OUT_F)[j];
                unsigned u2 = reinterpret_cast<const unsigned*>(
                    Whb + (size_t)q2.x * OUT_F)[j];
                unsigned u3 = reinterpret_cast<const unsigned*>(
                    Whb + (size_t)q3.x * OUT_F)[j];
                float att0 = __int_as_float(q0.y);
                float att1 = __int_as_float(q1.y);
                float att2 = __int_as_float(q2.y);
                float att3 = __int_as_float(q3.y);
                px = fmaf(att0, __uint_as_float((u0 & 0xffffu) << 16), px);
                py = fmaf(att0, __uint_as_float(u0 & 0xffff0000u), py);
                px = fmaf(att1, __uint_as_float((u1 & 0xffffu) << 16), px);
                py = fmaf(att1, __uint_as_float(u1 & 0xffff0000u), py);
                px = fmaf(att2, __uint_as_float((u2 & 0xffffu) << 16), px);
                py = fmaf(att2, __uint_as_float(u2 & 0xffff0000u), py);
                px = fmaf(att3, __uint_as_float((u3 & 0xffffu) << 16), px);
                py = fmaf(att3, __uint_as_float(u3 & 0xffff0000u), py);
            }
            for (; i < c; i += 2) {              // tail pair (maybe half-valid)
                int ii = i + h;
                bool val = ii < c;
                int2 q = sorted[lo + (val ? ii : i)];
                unsigned u = reinterpret_cast<const unsigned*>(
                    Whb + (size_t)q.x * OUT_F)[j];
                float att = val ? __int_as_float(q.y) : 0.0f;
                px = fmaf(att, __uint_as_float((u & 0xffffu) << 16), px);
                py = fmaf(att, __uint_as_float(u & 0xffff0000u), py);
            }
            ax[k] += px;
            ay[k] += py;
        }
        __syncthreads();
    }

#pragma unroll
    for (int k = 0; k < 8; k++) {
        float sx = ax[k] + __shfl_down(ax[k], 32, 64);
        float sy = ay[k] + __shfl_down(ay[k], 32, 64);
        int n = b * NPB + w * 8 + k;
        if (h == 0 && n < N_NODES) {
            float2 v;
            v.x = sx * ginv;
            v.y = sy * ginv;
            v.x = v.x > 0.0f ? v.x : expm1f(v.x);
            v.y = v.y > 0.0f ? v.y : expm1f(v.y);
            *reinterpret_cast<float2*>(out + (size_t)n * OUT_F + 2 * j) = v;
        }
    }
}

extern "C" void kernel_launch(void* const* d_in, const int* in_sizes, int n_in,
                              void* d_out, int out_size, void* d_ws, size_t ws_size,
                              hipStream_t stream) {
    const float* x  = (const float*)d_in[0];
    const int*   ei = (const int*)d_in[1];
    const float* W  = (const float*)d_in[2];
    const float* a  = (const float*)d_in[3];
    float* out = (float*)d_out;

    const int* src = ei;            // edge_index[0]
    const int* dst = ei + N_EDGES;  // edge_index[1]

    unsigned short* Whb = (unsigned short*)d_ws;      // 3,200,000 u16 = 6.4 MB
    float* sv     = (float*)(Whb + (size_t)N_NODES * OUT_F);  // 50,000 f
    float* tv     = sv + N_NODES;                     // 50,000 f
    float* psum   = tv + N_NODES;                     // 512 f
    int*   bcnt   = (int*)(psum + 512);               // NBUCK i
    int*   bbase  = bcnt + NBUCK;                     // NBUCK+1 i
    int*   cursor = bbase + NBUCK + 1;                // NBUCK i
    size_t used = (size_t)((char*)(cursor + NBUCK) - (char*)d_ws);
    used = (used + 15) & ~(size_t)15;
    int2*  rec  = (int2*)((char*)d_ws + used);        // 800,000 int2 = 6.4 MB

    hipMemsetAsync(bcnt, 0, NBUCK * sizeof(int), stream);
    k_wh<<<(N_NODES + 63) / 64, 256, 0, stream>>>(x, W, a, src, Whb, sv, tv, bcnt);
    k_bscan<<<1, 1024, 0, stream>>>(bcnt, bbase, cursor);
    k_binscatter<<<NBT, 256, 0, stream>>>(src, dst, sv, tv, cursor, rec, psum);
    k_bgather<<<NBUCK, 512, 0, stream>>>(bbase, rec, psum, Whb, out);
}